// Round 11
// baseline (236.057 us; speedup 1.0000x reference)
//
#include <hip/hip_runtime.h>

// LIF scan over T=16: mem_t = beta*mem + x_t - spk_{t-1}; spk_t = (mem_t - 1) > 0.
// Neurons independent -> 1 thread owns 8 neurons (2 dense f4 chunks) across all T.
//
// R14: overlap the per-pass drains. R12 (barrier-separated R/W bursts, 8-deep)
// won (+6% -> 226.9 headline); R13 (16-deep bursts) was null -> burst depth
// saturated at 8. Remaining structural cost of the scheme: each __syncthreads
// is s_waitcnt vmcnt(0)+s_barrier, so every pass serially exposes the load
// window AND the store-ack drain; only opposite-phase co-resident blocks hide
// these, and occupancy is GRID-limited at 2 blocks/CU (512 blocks / 256 CU).
// R14 keeps the proven 8-access burst but re-cuts geometry: 2 chunks x 4
// planes/pass x 4 passes, block span 2048 -> 1024 blocks = 4 blocks/CU (2x
// drain overlap), 8 barrier crossings instead of 16. VGPR ~64-84, well under
// the (256,4) 128-VGPR budget.
// Null => phase-separation saturated -> declare mixed-pattern envelope.
// Regression => revert to R12 as final.

constexpr int   T      = 16;
constexpr float BETA   = 0.9f;
constexpr float THRESH = 1.0f;

typedef float f4 __attribute__((ext_vector_type(4)));

__global__ __launch_bounds__(256, 4) void lif_kernel(const float* __restrict__ x,
                                                     float* __restrict__ out,
                                                     int n_per_t) {
    // No FMA contraction: must match numpy's two-rounding fp32 exactly, else
    // ~1-ulp drift flips spikes at the threshold (absmax = 1.0 cascades).
#pragma clang fp contract(off)
    // Block owns 2048 consecutive floats per plane as 2 chunks of 1024;
    // thread owns 2 f4 slots at c*1024 + tid*4. Clamp (not early-return) so
    // every thread reaches the barriers; with n_per_t = 2,097,152 and 1024
    // blocks the clamp never engages.
    int base = blockIdx.x * 2048 + threadIdx.x * 4;
    if (base + 1024 + 4 > n_per_t) base = 0;  // degenerate-safe duplicate work

    // Persistent recurrence state, registers only.
    f4 m[2] = {(f4)(0.f), (f4)(0.f)};
    f4 s[2] = {(f4)(0.f), (f4)(0.f)};

    for (int pass = 0; pass < 4; ++pass) {
        const int t0 = pass * 4;

        // READ region: 8 coalesced f4 loads (4 planes x 2 chunks), one
        // unidirectional burst per wave (proven-optimal depth, R12 vs R13).
        f4 r[4][2];
#pragma unroll
        for (int p = 0; p < 4; ++p) {
            const size_t off = (size_t)(t0 + p) * (size_t)n_per_t + (size_t)base;
#pragma unroll
            for (int c = 0; c < 2; ++c)
                r[p][c] = *reinterpret_cast<const f4*>(x + off + c * 1024);
        }

        // Compute: 4 recurrence steps; results overwrite r.
#pragma unroll
        for (int p = 0; p < 4; ++p) {
#pragma unroll
            for (int c = 0; c < 2; ++c) {
#pragma unroll
                for (int j = 0; j < 4; ++j) {
                    m[c][j] = BETA * m[c][j] + r[p][c][j] - s[c][j] * THRESH;
                    s[c][j] = (m[c][j] - THRESH) > 0.f ? 1.f : 0.f;
                }
                r[p][c] = s[c];
            }
        }

        // Region boundary: stores may not hoist above, loads may not sink below.
        __syncthreads();

        // WRITE region: 8-store unidirectional burst (plain cacheable stores).
#pragma unroll
        for (int p = 0; p < 4; ++p) {
            const size_t off = (size_t)(t0 + p) * (size_t)n_per_t + (size_t)base;
#pragma unroll
            for (int c = 0; c < 2; ++c)
                *reinterpret_cast<f4*>(out + off + c * 1024) = r[p][c];
        }

        // Region boundary: next pass's loads stay after this store burst.
        __syncthreads();
    }
}

extern "C" void kernel_launch(void* const* d_in, const int* in_sizes, int n_in,
                              void* d_out, int out_size, void* d_ws, size_t ws_size,
                              hipStream_t stream) {
    const float* x   = (const float*)d_in[0];
    float*       out = (float*)d_out;

    const int total   = in_sizes[0];      // 33,554,432
    const int n_per_t = total / T;        // 2,097,152 (divisible by 2048)
    const int blocks  = n_per_t / 2048;   // 1024 blocks = 4 blocks/CU

    lif_kernel<<<dim3(blocks), dim3(256), 0, stream>>>(x, out, n_per_t);
}

// Round 12
// 225.206 us; speedup vs baseline: 1.0482x; 1.0482x over previous
//
#include <hip/hip_runtime.h>

// LIF scan over T=16: mem_t = beta*mem + x_t - spk_{t-1}; spk_t = (mem_t - 1) > 0.
// Neurons independent -> 1 thread owns 16 neurons (4 dense f4 chunks) across all T.
//
// R15 = exact revert to R12, the measured session-best (headline 226.9 us;
// lif dispatches < 79.8 us, below even the harness's fillBuffer). Final
// confirmation run. The design space around this config is fully swept:
//   - burst depth 8 -> 16 (R13): null
//   - run length 16 KB -> 8 KB, 2 -> 4 planes/burst (R14): REGRESSION (84 us)
//   - blocks/CU 2 -> 4 (R14): no help
//   - store policy NT vs plain (R6): traffic identical, plain ~= NT
//   - per-wave asm fences (R4/R5/R9): all LOSE 10-25%
//   - occupancy 50% <-> 16% (R5-R8): invariant
// Winning mechanism (confirmed R12 vs R8/R13/R14): barrier-separated
// unidirectional R/W bursts with LONG dense runs (16 KB contiguous per plane,
// 2 planes per burst) minimize DRAM bus-turnaround + row-thrash across the
// forced 32-region strided pattern. Remaining gap to the 42-us logical floor
// is the pattern's intrinsic DRAM efficiency: every software lever swept.

constexpr int   T      = 16;
constexpr float BETA   = 0.9f;
constexpr float THRESH = 1.0f;

typedef float f4 __attribute__((ext_vector_type(4)));

__global__ __launch_bounds__(256, 4) void lif_kernel(const float* __restrict__ x,
                                                     float* __restrict__ out,
                                                     int n_per_t) {
    // No FMA contraction: must match numpy's two-rounding fp32 exactly, else
    // ~1-ulp drift flips spikes at the threshold (absmax = 1.0 cascades).
#pragma clang fp contract(off)
    // Block owns 4096 consecutive floats per plane as 4 chunks of 1024;
    // thread owns 4 f4 slots at c*1024 + tid*4. Clamp (not early-return) so
    // every thread reaches the barriers; with n_per_t = 2,097,152 and 512
    // blocks the clamp never engages.
    int base = blockIdx.x * 4096 + threadIdx.x * 4;
    if (base + 3072 + 4 > n_per_t) base = 0;  // degenerate-safe duplicate work

    // Persistent recurrence state, registers only.
    f4 m[4] = {(f4)(0.f), (f4)(0.f), (f4)(0.f), (f4)(0.f)};
    f4 s[4] = {(f4)(0.f), (f4)(0.f), (f4)(0.f), (f4)(0.f)};

    for (int pass = 0; pass < 8; ++pass) {
        const int t0 = pass * 2;

        // READ region: 8 coalesced f4 loads (2 planes x 4 chunks), one
        // unidirectional burst; 16 KB dense run per plane at block scope.
        f4 r[2][4];
#pragma unroll
        for (int p = 0; p < 2; ++p) {
            const size_t off = (size_t)(t0 + p) * (size_t)n_per_t + (size_t)base;
#pragma unroll
            for (int c = 0; c < 4; ++c)
                r[p][c] = *reinterpret_cast<const f4*>(x + off + c * 1024);
        }

        // Compute: 2 recurrence steps; results overwrite r.
#pragma unroll
        for (int p = 0; p < 2; ++p) {
#pragma unroll
            for (int c = 0; c < 4; ++c) {
#pragma unroll
                for (int j = 0; j < 4; ++j) {
                    m[c][j] = BETA * m[c][j] + r[p][c][j] - s[c][j] * THRESH;
                    s[c][j] = (m[c][j] - THRESH) > 0.f ? 1.f : 0.f;
                }
                r[p][c] = s[c];
            }
        }

        // Region boundary: stores may not hoist above, loads may not sink below.
        __syncthreads();

        // WRITE region: 8-store unidirectional burst (plain cacheable stores).
#pragma unroll
        for (int p = 0; p < 2; ++p) {
            const size_t off = (size_t)(t0 + p) * (size_t)n_per_t + (size_t)base;
#pragma unroll
            for (int c = 0; c < 4; ++c)
                *reinterpret_cast<f4*>(out + off + c * 1024) = r[p][c];
        }

        // Region boundary: next pass's loads stay after this store burst.
        __syncthreads();
    }
}

extern "C" void kernel_launch(void* const* d_in, const int* in_sizes, int n_in,
                              void* d_out, int out_size, void* d_ws, size_t ws_size,
                              hipStream_t stream) {
    const float* x   = (const float*)d_in[0];
    float*       out = (float*)d_out;

    const int total   = in_sizes[0];      // 33,554,432
    const int n_per_t = total / T;        // 2,097,152 (divisible by 4096)
    const int blocks  = n_per_t / 4096;   // 512 blocks, 256 threads, 16 floats/thread

    lif_kernel<<<dim3(blocks), dim3(256), 0, stream>>>(x, out, n_per_t);
}